// Round 10
// baseline (164.625 us; speedup 1.0000x reference)
//
#include <hip/hip_runtime.h>

#define S_LEN 4096
#define BATCH 2
#define DM 512
#define NH 8
#define DH 64
#define WINDOW 256

typedef __bf16 bf16x8 __attribute__((ext_vector_type(8)));
typedef float f32x4 __attribute__((ext_vector_type(4)));
typedef unsigned short u16x8 __attribute__((ext_vector_type(8)));

typedef const __attribute__((address_space(1))) unsigned int* gas_ptr;
typedef __attribute__((address_space(3))) unsigned int* las_ptr;

#define SCALE_LOG2E 0.1803368801111204f  // 0.125 * log2(e)
#define FIXED_MAX 16.0f                  // safe upper bound for log2-domain scores

// Raw barrier without the compiler's vmcnt(0)/lgkmcnt(0) drain.
#define BAR()                                   \
  do {                                          \
    asm volatile("" ::: "memory");              \
    __builtin_amdgcn_s_barrier();               \
    asm volatile("" ::: "memory");              \
  } while (0)
#define WAITVM(N) asm volatile("s_waitcnt vmcnt(" #N ")" ::: "memory")
#define WAITLGKM(N) asm volatile("s_waitcnt lgkmcnt(" #N ")" ::: "memory")

// native gfx950 bf16 convert, RNE
__device__ __forceinline__ unsigned short b16(float f) {
  __bf16 h = (__bf16)f;
  return __builtin_bit_cast(unsigned short, h);
}

__device__ __forceinline__ u16x8 pack8(float4 a, float4 b) {
  u16x8 r;
  r[0] = b16(a.x); r[1] = b16(a.y); r[2] = b16(a.z); r[3] = b16(a.w);
  r[4] = b16(b.x); r[5] = b16(b.y); r[6] = b16(b.z); r[7] = b16(b.w);
  return r;
}

// ---------------------------------------------------------------------------
// R10 (= R9 + race fix): eliminate convert_all (30 MB traffic + launch gap
// ~= 7 us of the 48.5 us kernel budget) by converting fp32->bf16 DURING GEMM
// staging. qkv: A (=x fp32) and B (=qkv_w fp32) reg-staged: global_load
// dwordx4 -> cvt -> swizzled ds_write_b128. LDS content layout bit-identical
// to the R6/R8 passing kernel (slot s of row r holds data chunk s^((r>>1)&3)).
// One barrier per K-iter: loads(k+1) issued early (REGISTER loads, no LDS
// hazard) -> lgkmcnt(0) -> BAR -> compute buf[cur] -> write buf[cur^1].
// RACE FIX vs R9: gemm_out's gload_lds DMA (writes LDS!) is issued AFTER
// BAR(), not before: sA[cur^1] is read by iter k-1 compute, and a slow wave
// may still be reading it until it arrives at BAR(k).
// ---------------------------------------------------------------------------

// QKV projection with fused convert, 128x128 tile, XCD-pinned 1D swizzle.
__global__ __launch_bounds__(256) void gemm_qkv(const float* __restrict__ x,
                                                const float* __restrict__ qw,
                                                const float* __restrict__ bias,
                                                unsigned short* __restrict__ Qb,
                                                unsigned short* __restrict__ Kb,
                                                unsigned short* __restrict__ Vt) {
  __shared__ __align__(16) unsigned short sA[2 * 128 * 32];
  __shared__ __align__(16) unsigned short sB[2 * 128 * 32];
  f32x4 acc[4][4] = {};
  const int id = blockIdx.x;
  const int X = id & 7;              // XCD slot
  const int t2 = id >> 3;
  const int cb = t2 % 12;            // column block 0..11
  const int rb = (t2 / 12) * 8 + X;  // row block 0..63, pinned to XCD X
  const int m0 = rb * 128, n0 = cb * 128;

  const int t = threadIdx.x;
  const int wave = t >> 6, lane = t & 63;
  const int wr = wave >> 1, wc = wave & 1;
  const int quad = lane >> 4, l16 = lane & 15;
  const int sw2 = (l16 >> 1) & 3;    // fragment-row swizzle bits
  const int cq = (quad ^ sw2) * 8;   // swizzled ushort offset of data chunk `quad`

  // staging roles: thread t owns row srow, chunks {2*shalf, 2*shalf+1}
  const int srow = t >> 1, shalf = t & 1;
  const int ssw = (srow >> 1) & 3;
  const int slot0 = ((shalf * 2) ^ ssw) * 8;      // swizzled ushort offsets
  const int slot1 = ((shalf * 2 + 1) ^ ssw) * 8;
  const float* ax = x + (size_t)(m0 + srow) * 512 + shalf * 16;
  const float* bx = qw + (size_t)(n0 + srow) * 512 + shalf * 16;

  float4 ra[4], rbv[4];
#define LOADREGS(k0)                                                    \
  do {                                                                  \
    const float* pa = ax + (k0);                                        \
    ra[0] = *(const float4*)(pa + 0);  ra[1] = *(const float4*)(pa + 4);\
    ra[2] = *(const float4*)(pa + 8);  ra[3] = *(const float4*)(pa + 12);\
    const float* pb = bx + (k0);                                        \
    rbv[0] = *(const float4*)(pb + 0); rbv[1] = *(const float4*)(pb + 4);\
    rbv[2] = *(const float4*)(pb + 8); rbv[3] = *(const float4*)(pb + 12);\
  } while (0)
#define WRITEREGS(buf)                                                  \
  do {                                                                  \
    unsigned short* wA = sA + (buf) * 4096 + srow * 32;                 \
    *(u16x8*)(wA + slot0) = pack8(ra[0], ra[1]);                        \
    *(u16x8*)(wA + slot1) = pack8(ra[2], ra[3]);                        \
    unsigned short* wB = sB + (buf) * 4096 + srow * 32;                 \
    *(u16x8*)(wB + slot0) = pack8(rbv[0], rbv[1]);                      \
    *(u16x8*)(wB + slot1) = pack8(rbv[2], rbv[3]);                      \
  } while (0)

  LOADREGS(0);
  WRITEREGS(0);  // compiler inserts the vmcnt waits before pack8 uses
  for (int k = 0; k < 16; ++k) {
    const int cur = k & 1;
    if (k < 15) LOADREGS(k * 32 + 32);  // register loads: issue early, no LDS hazard
    WAITLGKM(0);  // my ds_writes (prev iter / prologue) retired
    BAR();        // buf[cur] published to all waves
    const unsigned short* bA = sA + cur * 4096;
    const unsigned short* bB = sB + cur * 4096;
    bf16x8 af[4], bff[4];
#pragma unroll
    for (int i = 0; i < 4; ++i)
      af[i] = *(const bf16x8*)&bA[(wr * 64 + i * 16 + l16) * 32 + cq];
#pragma unroll
    for (int j = 0; j < 4; ++j)
      bff[j] = *(const bf16x8*)&bB[(wc * 64 + j * 16 + l16) * 32 + cq];
#pragma unroll
    for (int i = 0; i < 4; ++i)
#pragma unroll
      for (int j = 0; j < 4; ++j)
        acc[i][j] = __builtin_amdgcn_mfma_f32_16x16x32_bf16(af[i], bff[j], acc[i][j], 0, 0, 0);
    if (k < 15) WRITEREGS(cur ^ 1);  // after BAR(k): all waves done reading cur^1
  }
#undef LOADREGS
#undef WRITEREGS

#pragma unroll
  for (int j = 0; j < 4; ++j) {
    const int n = n0 + wc * 64 + j * 16 + l16;
    const float bv = bias[n];
#pragma unroll
    for (int i = 0; i < 4; ++i) {
      const int mr = m0 + wr * 64 + i * 16 + quad * 4;
      if (n < DM) {
#pragma unroll
        for (int r = 0; r < 4; ++r)
          Qb[(size_t)(mr + r) * DM + n] = b16((acc[i][j][r] + bv) * SCALE_LOG2E);
      } else if (n < 2 * DM) {
#pragma unroll
        for (int r = 0; r < 4; ++r)
          Kb[(size_t)(mr + r) * DM + (n - DM)] = b16(acc[i][j][r] + bv);
      } else {
        const int d = n & 63, h = (n - 2 * DM) >> 6;
#pragma unroll
        for (int r = 0; r < 4; ++r) {
          const int m = mr + r;
          const int b = m >> 12, s = m & (S_LEN - 1);
          Vt[((size_t)((b * NH + h) * DH + d)) * S_LEN + s] = b16(acc[i][j][r] + bv);
        }
      }
    }
  }
}

// Output projection, 64x128 tile: A = AO bf16 via gload_lds (inverse-source
// swizzle), B = out_w fp32 reg-converted. DMA issued AFTER the barrier
// (race fix); B reg loads ride along there too.
__global__ __launch_bounds__(256) void gemm_out(const unsigned short* __restrict__ Ab,
                                                const float* __restrict__ wb,
                                                const float* __restrict__ bias,
                                                float* __restrict__ C) {
  __shared__ __align__(16) unsigned short sA[2 * 64 * 32];
  __shared__ __align__(16) unsigned short sB[2 * 128 * 32];
  const int t = threadIdx.x;
  const int wave = t >> 6, lane = t & 63;
  const int wr = wave >> 1, wc = wave & 1;
  const int quad = lane >> 4, l16 = lane & 15;
  const int sw2 = (l16 >> 1) & 3;
  const int cq = (quad ^ sw2) * 8;
  const int id = blockIdx.x;
  const int X = id & 7;              // XCD slot
  const int t2 = id >> 3;
  const int cb = t2 % 4;             // column block 0..3
  const int rb = (t2 / 4) * 8 + X;   // row block 0..127, pinned to XCD X
  const int m0 = rb * 64, n0 = cb * 128;

  // B staging roles (128 rows x 32 k over 256 threads)
  const int srow = t >> 1, shalf = t & 1;
  const int ssw = (srow >> 1) & 3;
  const int slot0 = ((shalf * 2) ^ ssw) * 8;
  const int slot1 = ((shalf * 2 + 1) ^ ssw) * 8;
  const float* bx = wb + (size_t)(n0 + srow) * 512 + shalf * 16;
  // A staging (gload_lds): slot t holds data chunk (t&3)^((t>>3)&3) of row t>>2
  const int arow = t >> 2;
  const int acg = (t & 3) ^ ((t >> 3) & 3);
  const unsigned short* abase = Ab + (size_t)(m0 + arow) * 512 + acg * 8;

  float4 rbv[4];
#define OUT_LOAD(k0, buf)                                               \
  do {                                                                  \
    __builtin_amdgcn_global_load_lds(                                   \
        (gas_ptr)(const void*)(abase + (k0)),                           \
        (las_ptr)(void*)(sA + (buf) * 2048 + wave * 512), 16, 0, 0);    \
    const float* pb = bx + (k0);                                        \
    rbv[0] = *(const float4*)(pb + 0); rbv[1] = *(const float4*)(pb + 4);\
    rbv[2] = *(const float4*)(pb + 8); rbv[3] = *(const float4*)(pb + 12);\
  } while (0)
#define OUT_WRITE(buf)                                                  \
  do {                                                                  \
    unsigned short* wB = sB + (buf) * 4096 + srow * 32;                 \
    *(u16x8*)(wB + slot0) = pack8(rbv[0], rbv[1]);                      \
    *(u16x8*)(wB + slot1) = pack8(rbv[2], rbv[3]);                      \
  } while (0)

  f32x4 acc[2][4] = {};
  OUT_LOAD(0, 0);
  WAITVM(0);      // A(0) DMA landed + B(0) regs
  OUT_WRITE(0);
  for (int k = 0; k < 16; ++k) {
    const int cur = k & 1;
    WAITLGKM(0);  // my ds_writes retired
    BAR();        // buf[cur] published; all waves done reading buf[cur^1]
    if (k < 15) OUT_LOAD(k * 32 + 32, cur ^ 1);  // DMA into cur^1 now safe
    const unsigned short* bA = sA + cur * 2048;
    const unsigned short* bB = sB + cur * 4096;
    bf16x8 af[2], bff[4];
#pragma unroll
    for (int i = 0; i < 2; ++i)
      af[i] = *(const bf16x8*)&bA[(wr * 32 + i * 16 + l16) * 32 + cq];
#pragma unroll
    for (int j = 0; j < 4; ++j)
      bff[j] = *(const bf16x8*)&bB[(wc * 64 + j * 16 + l16) * 32 + cq];
#pragma unroll
    for (int i = 0; i < 2; ++i)
#pragma unroll
      for (int j = 0; j < 4; ++j)
        acc[i][j] = __builtin_amdgcn_mfma_f32_16x16x32_bf16(af[i], bff[j], acc[i][j], 0, 0, 0);
    if (k < 15) {
      WAITVM(0);  // A(k+1) DMA + B(k+1) regs landed (issued before compute)
      OUT_WRITE(cur ^ 1);
    }
  }
#undef OUT_LOAD
#undef OUT_WRITE

#pragma unroll
  for (int j = 0; j < 4; ++j) {
    const int n = n0 + wc * 64 + j * 16 + l16;
    const float bv = bias[n];
#pragma unroll
    for (int i = 0; i < 2; ++i) {
      const int mr = m0 + wr * 32 + i * 16 + quad * 4;
#pragma unroll
      for (int r = 0; r < 4; ++r)
        C[(size_t)(mr + r) * DM + n] = acc[i][j][r] + bv;
    }
  }
}

// MFMA flash attention, XOR-swizzled dbuf LDS staging via global_load_lds.
// (Unchanged from the passing R6/R8 kernel.)
__global__ __launch_bounds__(256) void attn_mfma(const unsigned short* __restrict__ Qb,
                                                 const unsigned short* __restrict__ Kb,
                                                 const unsigned short* __restrict__ Vt,
                                                 unsigned short* __restrict__ AO) {
  __shared__ __align__(16) unsigned short Ks[2 * 64 * 64];
  __shared__ __align__(16) unsigned short Vs[2 * 64 * 64];  // V^T chunk: [d][seq]
  __shared__ __align__(16) unsigned short Ps[64 * 64];      // P: [query][key], XOR-swizzled
  const int t = threadIdx.x;
  const int wave = t >> 6, lane = t & 63;
  const int quad = lane >> 4, l16 = lane & 15;

  const int id = blockIdx.x;
  const int X = id & 7;
  const int o = (id >> 3) & 7;
  const int h = (id >> 6) & 7;
  const int b = id >> 9;
  const int g = (X - h) & 7;          // group of 8 q-tiles pinned to XCD X
  const int qt = g * 8 + o;           // q-tile index 0..63
  const int q0 = qt * 64;

  const unsigned short* Kbase = Kb + (size_t)b * S_LEN * DM + h * DH;
  const unsigned short* Vbase = Vt + (size_t)((b * NH + h) * DH) * S_LEN;

  const unsigned short* qrow =
      Qb + (size_t)(b * S_LEN + q0 + wave * 16 + l16) * DM + h * DH;
  const bf16x8 aq0 = *(const bf16x8*)(qrow + quad * 8);
  const bf16x8 aq1 = *(const bf16x8*)(qrow + 32 + quad * 8);

  const int first = (qt >= 4) ? 0 : (4 - qt);  // first valid chunk

  int grow[2], gcol[2];
#pragma unroll
  for (int s = 0; s < 2; ++s) {
    const int L = t + 256 * s;
    grow[s] = L >> 3;
    gcol[s] = ((L & 7) ^ (grow[s] & 7)) * 8;
  }

#define ATTN_STAGE(c0, buf)                                                       \
  do {                                                                            \
    _Pragma("unroll") for (int s = 0; s < 2; ++s) {                               \
      const unsigned short* gk = Kbase + (size_t)((c0) + grow[s]) * DM + gcol[s]; \
      __builtin_amdgcn_global_load_lds(                                           \
          (gas_ptr)(const void*)gk,                                               \
          (las_ptr)(void*)(Ks + (buf) * 4096 + wave * 512 + s * 2048), 16, 0, 0); \
      const unsigned short* gv = Vbase + (size_t)grow[s] * S_LEN + (c0) + gcol[s];\
      __builtin_amdgcn_global_load_lds(                                           \
          (gas_ptr)(const void*)gv,                                               \
          (las_ptr)(void*)(Vs + (buf) * 4096 + wave * 512 + s * 2048), 16, 0, 0); \
    }                                                                             \
  } while (0)

  ATTN_STAGE(q0 - WINDOW + first * 64, first & 1);

  float l_ = 0.f;
  f32x4 O[4] = {};

  const int sw = l16 & 7;
  const int c0q = (quad ^ sw) * 8;
  const int c1q = ((quad | 4) ^ sw) * 8;

#pragma unroll
  for (int c = 0; c < 5; ++c) {
    if (c < first) continue;  // block-uniform
    const int c0 = q0 - WINDOW + c * 64;
    const int cur = c & 1;
    BAR();
    if (c < 4) {
      ATTN_STAGE(c0 + 64, cur ^ 1);
      WAITVM(4);
    } else {
      WAITVM(0);
    }
    BAR();

    const unsigned short* Kc = Ks + cur * 4096;
    const unsigned short* Vc = Vs + cur * 4096;

    f32x4 sc[4];
#pragma unroll
    for (int nt = 0; nt < 4; ++nt) {
      const int krow = (nt * 16 + l16) * 64;
      bf16x8 bk0 = *(const bf16x8*)&Kc[krow + c0q];
      bf16x8 bk1 = *(const bf16x8*)&Kc[krow + c1q];
      f32x4 z = {};
      z = __builtin_amdgcn_mfma_f32_16x16x32_bf16(bk0, aq0, z, 0, 0, 0);
      sc[nt] = __builtin_amdgcn_mfma_f32_16x16x32_bf16(bk1, aq1, z, 0, 0, 0);
    }

    const int iiq = wave * 16 + l16;
    const int prow = iiq * 64;
#pragma unroll
    for (int nt = 0; nt < 4; ++nt) {
#pragma unroll
      for (int r = 0; r < 4; ++r) {
        const int jjk = nt * 16 + quad * 4 + r;
        float p = exp2f(sc[nt][r] - FIXED_MAX);
        if (c == 0) p = (jjk >= iiq) ? p : 0.f;
        if (c == 4) p = (jjk <= iiq) ? p : 0.f;
        sc[nt][r] = p;
        l_ += p;
      }
      ushort4 pk;
      pk.x = b16(sc[nt][0]);
      pk.y = b16(sc[nt][1]);
      pk.z = b16(sc[nt][2]);
      pk.w = b16(sc[nt][3]);
      *(ushort4*)&Ps[prow + (((nt * 2 + (quad >> 1)) ^ sw) * 8) + (quad & 1) * 4] = pk;
    }

    const bf16x8 bp0 = *(const bf16x8*)&Ps[prow + c0q];
    const bf16x8 bp1 = *(const bf16x8*)&Ps[prow + c1q];

#pragma unroll
    for (int nt = 0; nt < 4; ++nt) {
      const int vrow = (nt * 16 + l16) * 64;
      bf16x8 bv0 = *(const bf16x8*)&Vc[vrow + c0q];
      bf16x8 bv1 = *(const bf16x8*)&Vc[vrow + c1q];
      O[nt] = __builtin_amdgcn_mfma_f32_16x16x32_bf16(bv0, bp0, O[nt], 0, 0, 0);
      O[nt] = __builtin_amdgcn_mfma_f32_16x16x32_bf16(bv1, bp1, O[nt], 0, 0, 0);
    }
  }
#undef ATTN_STAGE

  l_ += __shfl_xor(l_, 16);
  l_ += __shfl_xor(l_, 32);
  const float linv = 1.f / l_;

  unsigned short* aoRow =
      AO + (size_t)(b * S_LEN + q0 + wave * 16 + l16) * DM + h * DH;
#pragma unroll
  for (int nt = 0; nt < 4; ++nt) {
    ushort4 o4;
    o4.x = b16(O[nt][0] * linv);
    o4.y = b16(O[nt][1] * linv);
    o4.z = b16(O[nt][2] * linv);
    o4.w = b16(O[nt][3] * linv);
    *(ushort4*)(aoRow + nt * 16 + quad * 4) = o4;
  }
}

extern "C" void kernel_launch(void* const* d_in, const int* in_sizes, int n_in,
                              void* d_out, int out_size, void* d_ws, size_t ws_size,
                              hipStream_t stream) {
  const float* x = (const float*)d_in[0];
  const float* qkv_w = (const float*)d_in[1];
  const float* qkv_b = (const float*)d_in[2];
  const float* out_w = (const float*)d_in[3];
  const float* out_b = (const float*)d_in[4];
  float* out = (float*)d_out;

  const int M = BATCH * S_LEN;  // 8192
  unsigned short* ws = (unsigned short*)d_ws;
  unsigned short* Qb = ws;                       // 8192*512
  unsigned short* Kb = Qb + (size_t)M * DM;      // 8192*512
  unsigned short* Vt = Kb + (size_t)M * DM;      // 2*8*64*4096
  unsigned short* AO = Vt + (size_t)M * DM;      // 8192*512

  gemm_qkv<<<768, 256, 0, stream>>>(x, qkv_w, qkv_b, Qb, Kb, Vt);

  attn_mfma<<<1024, 256, 0, stream>>>(Qb, Kb, Vt, AO);

  gemm_out<<<512, 256, 0, stream>>>(AO, out_w, out_b, out);
}